// Round 7
// baseline (122.388 us; speedup 1.0000x reference)
//
#include <hip/hip_runtime.h>

#define L_TOK 4096
#define D_DIM 2048
#define R_STEPS 10
#define G_TOK 410
#define NROWS 1640
#define FB_NBLK 256

typedef unsigned int uint;
typedef unsigned long long u64;

// ws layout (bytes), zeroed each call:
// [0,1280)     flagset[r*32]  (speculative kernel's computed flags, stride 128B)
// [2048,3328)  flags2[r*32]   (fallback's exact flags)
// [3968,3976)  barrier {count, generation}

__device__ __forceinline__ void load8(float* v, const float* p) {
  float4 a = *(const float4*)p;
  float4 b = *(const float4*)(p + 4);
  v[0] = a.x; v[1] = a.y; v[2] = a.z; v[3] = a.w;
  v[4] = b.x; v[5] = b.y; v[6] = b.z; v[7] = b.w;
}
__device__ __forceinline__ void zero8(float* v) {
#pragma unroll
  for (int i = 0; i < 8; ++i) v[i] = 0.0f;
}
__device__ __forceinline__ void store8(float* p, const float* v) {
  *(float4*)p = make_float4(v[0], v[1], v[2], v[3]);
  *(float4*)(p + 4) = make_float4(v[4], v[5], v[6], v[7]);
}

// ---------------- speculative kernel: assume every step's flag == 1 ----------------
// launch_bounds(256,8): 8 waves/EU -> 8 blocks/CU -> all 1640 blocks co-resident
// (6.4/CU), eliminating the two-batch tail seen at (256,4). R5 measured 32 VGPR
// under this bound with the same structure.
__global__ __launch_bounds__(256, 8) void qact_spec(
    const float* __restrict__ x, const float* __restrict__ s,
    float* __restrict__ y, uint* __restrict__ flagset) {
  __shared__ float redA[2][4], redB[2][4];
  __shared__ double redS[2][4][2];

  const int tid = threadIdx.x, lane = tid & 63, wid = tid >> 6;
  const int row = blockIdx.x;
  const int b = row / G_TOK, g = row % G_TOK;
  const size_t base = ((size_t)b * L_TOK + (size_t)g * R_STEPS) * D_DIM + (size_t)tid * 8;

  uint m = 0;  // this thread's 8 outlier-mask bits (carried across steps)
  float cur[8], nxt[8];
  load8(cur, x + base);  // token g*10 always < 4096

  for (int r = 0; r < R_STEPS; ++r) {
    const int tok = g * R_STEPS + r;
    const bool valid = tok < L_TOK;  // block-uniform
    const int buf = r & 1;           // double-buffered shared (one sync per step)
    const float sv = valid ? s[tok] : 1.0f;

    // prefetch next token slab (independent of mask state) — hides HBM latency
    if (r + 1 < R_STEPS) {
      if (tok + 1 < L_TOK) load8(nxt, x + base + (size_t)(r + 1) * D_DIM);
      else zero8(nxt);
    }

    // ---- single fused reduction pass ----
    // A  = max |x| over OLD-unmasked (for flag + newly-masked max)
    // Bm = max |x| over OLD-masked   (for outlier scale)
    // S1,S2 = fp64 sums of a, a^2 over OLD-unmasked (for mean/std)
    float a[8];
    float A = 0.0f, Bm = 0.0f;
    double S1 = 0.0, S2 = 0.0;
#pragma unroll
    for (int i = 0; i < 8; ++i) {
      const bool bit = (m >> i) & 1u;
      const float fa = fabsf(cur[i]);
      a[i] = bit ? 0.0f : fa;
      A = fmaxf(A, a[i]);
      Bm = bit ? fmaxf(Bm, fa) : Bm;
      const double ad = (double)a[i];
      S1 += ad;
      S2 += ad * ad;
    }
#pragma unroll
    for (int o = 32; o > 0; o >>= 1) {
      A = fmaxf(A, __shfl_down(A, o, 64));
      Bm = fmaxf(Bm, __shfl_down(Bm, o, 64));
      S1 += __shfl_down(S1, o, 64);
      S2 += __shfl_down(S2, o, 64);
    }
    if (lane == 0) {
      redA[buf][wid] = A; redB[buf][wid] = Bm;
      redS[buf][wid][0] = S1; redS[buf][wid][1] = S2;
    }
    __syncthreads();
    A = fmaxf(fmaxf(redA[buf][0], redA[buf][1]), fmaxf(redA[buf][2], redA[buf][3]));
    Bm = fmaxf(fmaxf(redB[buf][0], redB[buf][1]), fmaxf(redB[buf][2], redB[buf][3]));
    S1 = redS[buf][0][0] + redS[buf][1][0] + redS[buf][2][0] + redS[buf][3][0];
    S2 = redS[buf][0][1] + redS[buf][1][1] + redS[buf][2][1] + redS[buf][3][1];

    if (tid == 0) {
      if (A / 7.0f > sv) atomicOr(&flagset[r * 32], 1u);  // record exact contribution
    }

    // ---- mask update under flag=1 assumption: a > mean + 3*std(ddof=1) ----
    const double n = (double)D_DIM;
    const double mean = S1 / n;
    double var = (S2 - n * mean * mean) / (n - 1.0);
    var = var > 0.0 ? var : 0.0;
    const double thr = mean + 3.0 * sqrt(var);
#pragma unroll
    for (int i = 0; i < 8; ++i)
      if ((double)a[i] > thr) m |= (1u << i);

    // outlier dynamic scale via identity: newly-masked max == A iff A > thr
    const float O = ((double)A > thr) ? fmaxf(Bm, A) : Bm;
    const float os = fmaxf(O, 1e-8f) / 127.0f;

    // ---- quantize + store (single divide per element: paths are disjoint) ----
    if (valid) {
      float out[8];
#pragma unroll
      for (int i = 0; i < 8; ++i) {
        const bool mm = (m >> i) & 1u;
        const float d = mm ? os : sv;
        const float bound = mm ? 127.0f : 7.0f;
        float q = rintf(cur[i] / d);
        q = fminf(fmaxf(q, -bound), bound);
        out[i] = q * d;
      }
      store8(y + base + (size_t)r * D_DIM, out);
    }

#pragma unroll
    for (int i = 0; i < 8; ++i) cur[i] = nxt[i];
  }
}

// ---------------- fallback: exact sequential, runs only if speculation failed ----------------
__device__ __forceinline__ void grid_barrier(uint* cnt, uint* gen) {
  __syncthreads();
  if (threadIdx.x == 0) {
    const uint my = __hip_atomic_load(gen, __ATOMIC_ACQUIRE, __HIP_MEMORY_SCOPE_AGENT);
    const uint old = __hip_atomic_fetch_add(cnt, 1u, __ATOMIC_ACQ_REL, __HIP_MEMORY_SCOPE_AGENT);
    if (old == FB_NBLK - 1) {
      __hip_atomic_store(cnt, 0u, __ATOMIC_RELAXED, __HIP_MEMORY_SCOPE_AGENT);
      __hip_atomic_store(gen, my + 1u, __ATOMIC_RELEASE, __HIP_MEMORY_SCOPE_AGENT);
    } else {
      while (__hip_atomic_load(gen, __ATOMIC_ACQUIRE, __HIP_MEMORY_SCOPE_AGENT) == my)
        __builtin_amdgcn_s_sleep(8);
    }
  }
  __syncthreads();
}

__global__ __launch_bounds__(256, 2) void qact_fallback(
    const float* __restrict__ x, const float* __restrict__ s, float* __restrict__ y,
    const uint* __restrict__ flagset, uint* __restrict__ flags2, uint* __restrict__ bar) {
  // If every speculative flag came out 1, speculation was exact (induction) -> done.
  bool ok = true;
#pragma unroll
  for (int r = 0; r < R_STEPS; ++r) ok &= (flagset[r * 32] != 0u);
  if (ok) return;

  __shared__ float redM[4];
  __shared__ double redS[4][2];
  __shared__ float redO[4];

  const int tid = threadIdx.x, lane = tid & 63, wid = tid >> 6;
  u64 mask = 0;  // 7 rows x 8 bits

  for (int r = 0; r < R_STEPS; ++r) {
    // ---- phase A: exact flag contributions with current masks ----
    for (int j = 0; j < 7; ++j) {
      const int row = blockIdx.x + FB_NBLK * j;
      if (row >= NROWS) break;  // block-uniform
      const int b = row / G_TOK, g = row % G_TOK;
      const int tok = g * R_STEPS + r;
      float A = 0.0f;
      if (tok < L_TOK) {
        const size_t off = ((size_t)b * L_TOK + tok) * D_DIM + (size_t)tid * 8;
        float v[8];
        load8(v, x + off);
        const uint mj = (uint)(mask >> (j * 8)) & 0xffu;
#pragma unroll
        for (int i = 0; i < 8; ++i)
          if (!((mj >> i) & 1u)) A = fmaxf(A, fabsf(v[i]));
      }
#pragma unroll
      for (int o = 32; o > 0; o >>= 1) A = fmaxf(A, __shfl_down(A, o, 64));
      if (lane == 0) redM[wid] = A;
      __syncthreads();
      A = fmaxf(fmaxf(redM[0], redM[1]), fmaxf(redM[2], redM[3]));
      const float sv = (tok < L_TOK) ? s[tok] : 1.0f;
      if (tid == 0 && A / 7.0f > sv) atomicOr(&flags2[r * 32], 1u);
      __syncthreads();
    }

    grid_barrier(&bar[0], &bar[1]);

    const uint f = __hip_atomic_load(&flags2[r * 32], __ATOMIC_ACQUIRE, __HIP_MEMORY_SCOPE_AGENT);

    // ---- phase B: mask update (if f), quantize, store ----
    for (int j = 0; j < 7; ++j) {
      const int row = blockIdx.x + FB_NBLK * j;
      if (row >= NROWS) break;
      const int b = row / G_TOK, g = row % G_TOK;
      const int tok = g * R_STEPS + r;
      const bool valid = tok < L_TOK;
      const size_t off = ((size_t)b * L_TOK + (valid ? tok : 0)) * D_DIM + (size_t)tid * 8;
      float v[8];
      if (valid) load8(v, x + off);
      else zero8(v);
      uint mj = (uint)(mask >> (j * 8)) & 0xffu;
      float a[8];
#pragma unroll
      for (int i = 0; i < 8; ++i) a[i] = ((mj >> i) & 1u) ? 0.0f : fabsf(v[i]);
      if (f) {  // grid-uniform
        double S1 = 0.0, S2 = 0.0;
#pragma unroll
        for (int i = 0; i < 8; ++i) {
          S1 += (double)a[i];
          S2 += (double)a[i] * (double)a[i];
        }
#pragma unroll
        for (int o = 32; o > 0; o >>= 1) {
          S1 += __shfl_down(S1, o, 64);
          S2 += __shfl_down(S2, o, 64);
        }
        if (lane == 0) { redS[wid][0] = S1; redS[wid][1] = S2; }
        __syncthreads();
        S1 = redS[0][0] + redS[1][0] + redS[2][0] + redS[3][0];
        S2 = redS[0][1] + redS[1][1] + redS[2][1] + redS[3][1];
        const double n = (double)D_DIM;
        const double mean = S1 / n;
        double var = (S2 - n * mean * mean) / (n - 1.0);
        var = var > 0.0 ? var : 0.0;
        const double thr = mean + 3.0 * sqrt(var);
#pragma unroll
        for (int i = 0; i < 8; ++i)
          if ((double)a[i] > thr) mj |= (1u << i);
        mask = (mask & ~((u64)0xffu << (j * 8))) | ((u64)mj << (j * 8));
        __syncthreads();
      }
      if (valid) {
        float O = 0.0f;
#pragma unroll
        for (int i = 0; i < 8; ++i)
          if ((mj >> i) & 1u) O = fmaxf(O, fabsf(v[i]));
#pragma unroll
        for (int o = 32; o > 0; o >>= 1) O = fmaxf(O, __shfl_down(O, o, 64));
        if (lane == 0) redO[wid] = O;
        __syncthreads();
        O = fmaxf(fmaxf(redO[0], redO[1]), fmaxf(redO[2], redO[3]));
        const float os = fmaxf(O, 1e-8f) / 127.0f;
        const float sv = s[tok];
        float out[8];
#pragma unroll
        for (int i = 0; i < 8; ++i) {
          const bool mm = (mj >> i) & 1u;
          const float inl = mm ? 0.0f : v[i];
          const float orr = mm ? v[i] : 0.0f;
          const float qi = fminf(fmaxf(rintf(inl / sv), -7.0f), 7.0f);
          const float qo = fminf(fmaxf(rintf(orr / os), -127.0f), 127.0f);
          out[i] = qi * sv + qo * os;
        }
        store8(y + off, out);
        __syncthreads();
      }
    }
  }
}

extern "C" void kernel_launch(void* const* d_in, const int* in_sizes, int n_in,
                              void* d_out, int out_size, void* d_ws, size_t ws_size,
                              hipStream_t stream) {
  const float* x = (const float*)d_in[0];
  const float* s = (const float*)d_in[1];
  float* y = (float*)d_out;
  uint* flagset = (uint*)d_ws;
  uint* flags2 = (uint*)((char*)d_ws + 2048);
  uint* bar = (uint*)((char*)d_ws + 3968);

  (void)hipMemsetAsync(d_ws, 0, 4096, stream);
  qact_spec<<<NROWS, 256, 0, stream>>>(x, s, y, flagset);
  qact_fallback<<<FB_NBLK, 256, 0, stream>>>(x, s, y, flagset, flags2, bar);
}

// Round 8
// 92.872 us; speedup vs baseline: 1.3178x; 1.3178x over previous
//
#include <hip/hip_runtime.h>

#define L_TOK 4096
#define D_DIM 2048
#define R_STEPS 10
#define G_TOK 410
#define NROWS 1640
#define NBLK 820   // 2 rows per block: one residency wave at 4 blocks/CU
#define FB_NBLK 256

typedef unsigned int uint;
typedef unsigned long long u64;

// ws layout (bytes), zeroed each call:
// [0,1280)     flagset[r*32]  (speculative kernel's computed flags, stride 128B)
// [2048,3328)  flags2[r*32]   (fallback's exact flags)
// [3968,3976)  barrier {count, generation}

__device__ __forceinline__ void load8(float* v, const float* p) {
  float4 a = *(const float4*)p;
  float4 b = *(const float4*)(p + 4);
  v[0] = a.x; v[1] = a.y; v[2] = a.z; v[3] = a.w;
  v[4] = b.x; v[5] = b.y; v[6] = b.z; v[7] = b.w;
}
__device__ __forceinline__ void zero8(float* v) {
#pragma unroll
  for (int i = 0; i < 8; ++i) v[i] = 0.0f;
}
__device__ __forceinline__ void store8(float* p, const float* v) {
  *(float4*)p = make_float4(v[0], v[1], v[2], v[3]);
  *(float4*)(p + 4) = make_float4(v[4], v[5], v[6], v[7]);
}

// ---------------- speculative kernel: assume every step's flag == 1 ----------------
// 2 rows/block: 820 blocks <= 1024 residency slots at (256,4) -> no tail batch,
// and two independent dependency chains per thread (2x ILP on the
// load -> shuffle-reduce -> sqrt -> divide critical path).
// (256,8) is a measured loser: per-XCD-L2 footprint doubles -> thrash
// (R7: FETCH 66->125 MB, WRITE 132->239 MB).
__global__ __launch_bounds__(256, 4) void qact_spec(
    const float* __restrict__ x, const float* __restrict__ s,
    float* __restrict__ y, uint* __restrict__ flagset) {
  __shared__ float redA[2][4][2], redB[2][4][2];
  __shared__ double redS[2][4][4];

  const int tid = threadIdx.x, lane = tid & 63, wid = tid >> 6;
  const int row0 = blockIdx.x * 2, row1 = row0 + 1;
  const int b0 = row0 / G_TOK, g0 = row0 % G_TOK;
  const int b1 = row1 / G_TOK, g1 = row1 % G_TOK;
  const size_t base0 = ((size_t)b0 * L_TOK + (size_t)g0 * R_STEPS) * D_DIM + (size_t)tid * 8;
  const size_t base1 = ((size_t)b1 * L_TOK + (size_t)g1 * R_STEPS) * D_DIM + (size_t)tid * 8;

  uint m0 = 0, m1 = 0;  // per-thread 8-bit outlier masks (carried state)
  float cur0[8], cur1[8], nxt0[8], nxt1[8];
  load8(cur0, x + base0);  // token g*10 always < 4096
  load8(cur1, x + base1);

  for (int r = 0; r < R_STEPS; ++r) {
    const int tok0 = g0 * R_STEPS + r;
    const int tok1 = g1 * R_STEPS + r;
    const bool v0 = tok0 < L_TOK, v1 = tok1 < L_TOK;
    const int buf = r & 1;  // double-buffered shared (one sync per step)
    const float sv0 = v0 ? s[tok0] : 1.0f;
    const float sv1 = v1 ? s[tok1] : 1.0f;

    // prefetch next token slabs before the reduction — hides HBM latency
    if (r + 1 < R_STEPS) {
      if (tok0 + 1 < L_TOK) load8(nxt0, x + base0 + (size_t)(r + 1) * D_DIM);
      else zero8(nxt0);
      if (tok1 + 1 < L_TOK) load8(nxt1, x + base1 + (size_t)(r + 1) * D_DIM);
      else zero8(nxt1);
    }

    // ---- fused reduction pass, both rows interleaved ----
    // A  = max |x| over OLD-unmasked (flag + newly-masked max)
    // Bm = max |x| over OLD-masked   (outlier scale)
    // S1,S2 = fp64 sums of a, a^2 over OLD-unmasked (mean/std)
    float a0[8], a1[8];
    float A0 = 0.0f, Bm0 = 0.0f, A1 = 0.0f, Bm1 = 0.0f;
    double S1_0 = 0.0, S2_0 = 0.0, S1_1 = 0.0, S2_1 = 0.0;
#pragma unroll
    for (int i = 0; i < 8; ++i) {
      const bool bit0 = (m0 >> i) & 1u;
      const bool bit1 = (m1 >> i) & 1u;
      const float fa0 = fabsf(cur0[i]);
      const float fa1 = fabsf(cur1[i]);
      a0[i] = bit0 ? 0.0f : fa0;
      a1[i] = bit1 ? 0.0f : fa1;
      A0 = fmaxf(A0, a0[i]);
      A1 = fmaxf(A1, a1[i]);
      Bm0 = bit0 ? fmaxf(Bm0, fa0) : Bm0;
      Bm1 = bit1 ? fmaxf(Bm1, fa1) : Bm1;
      const double d0 = (double)a0[i], d1 = (double)a1[i];
      S1_0 += d0; S2_0 += d0 * d0;
      S1_1 += d1; S2_1 += d1 * d1;
    }
#pragma unroll
    for (int o = 32; o > 0; o >>= 1) {
      A0 = fmaxf(A0, __shfl_down(A0, o, 64));
      A1 = fmaxf(A1, __shfl_down(A1, o, 64));
      Bm0 = fmaxf(Bm0, __shfl_down(Bm0, o, 64));
      Bm1 = fmaxf(Bm1, __shfl_down(Bm1, o, 64));
      S1_0 += __shfl_down(S1_0, o, 64);
      S1_1 += __shfl_down(S1_1, o, 64);
      S2_0 += __shfl_down(S2_0, o, 64);
      S2_1 += __shfl_down(S2_1, o, 64);
    }
    if (lane == 0) {
      redA[buf][wid][0] = A0; redA[buf][wid][1] = A1;
      redB[buf][wid][0] = Bm0; redB[buf][wid][1] = Bm1;
      redS[buf][wid][0] = S1_0; redS[buf][wid][1] = S2_0;
      redS[buf][wid][2] = S1_1; redS[buf][wid][3] = S2_1;
    }
    __syncthreads();
    A0 = fmaxf(fmaxf(redA[buf][0][0], redA[buf][1][0]), fmaxf(redA[buf][2][0], redA[buf][3][0]));
    A1 = fmaxf(fmaxf(redA[buf][0][1], redA[buf][1][1]), fmaxf(redA[buf][2][1], redA[buf][3][1]));
    Bm0 = fmaxf(fmaxf(redB[buf][0][0], redB[buf][1][0]), fmaxf(redB[buf][2][0], redB[buf][3][0]));
    Bm1 = fmaxf(fmaxf(redB[buf][0][1], redB[buf][1][1]), fmaxf(redB[buf][2][1], redB[buf][3][1]));
    S1_0 = redS[buf][0][0] + redS[buf][1][0] + redS[buf][2][0] + redS[buf][3][0];
    S2_0 = redS[buf][0][1] + redS[buf][1][1] + redS[buf][2][1] + redS[buf][3][1];
    S1_1 = redS[buf][0][2] + redS[buf][1][2] + redS[buf][2][2] + redS[buf][3][2];
    S2_1 = redS[buf][0][3] + redS[buf][1][3] + redS[buf][2][3] + redS[buf][3][3];

    if (tid == 0) {
      if ((A0 / 7.0f > sv0) || (A1 / 7.0f > sv1)) atomicOr(&flagset[r * 32], 1u);
    }

    // ---- mask update under flag=1 assumption: a > mean + 3*std(ddof=1) ----
    const double n = (double)D_DIM;
    const double mean0 = S1_0 / n, mean1 = S1_1 / n;
    double var0 = (S2_0 - n * mean0 * mean0) / (n - 1.0);
    double var1 = (S2_1 - n * mean1 * mean1) / (n - 1.0);
    var0 = var0 > 0.0 ? var0 : 0.0;
    var1 = var1 > 0.0 ? var1 : 0.0;
    const double thr0 = mean0 + 3.0 * sqrt(var0);
    const double thr1 = mean1 + 3.0 * sqrt(var1);
#pragma unroll
    for (int i = 0; i < 8; ++i) {
      if ((double)a0[i] > thr0) m0 |= (1u << i);
      if ((double)a1[i] > thr1) m1 |= (1u << i);
    }

    // outlier dynamic scale via identity: newly-masked max == A iff A > thr
    const float O0 = ((double)A0 > thr0) ? fmaxf(Bm0, A0) : Bm0;
    const float O1 = ((double)A1 > thr1) ? fmaxf(Bm1, A1) : Bm1;
    const float os0 = fmaxf(O0, 1e-8f) / 127.0f;
    const float os1 = fmaxf(O1, 1e-8f) / 127.0f;

    // ---- quantize + store (single divide per element: paths are disjoint) ----
    if (v0) {
      float out[8];
#pragma unroll
      for (int i = 0; i < 8; ++i) {
        const bool mm = (m0 >> i) & 1u;
        const float d = mm ? os0 : sv0;
        const float bound = mm ? 127.0f : 7.0f;
        float q = rintf(cur0[i] / d);
        q = fminf(fmaxf(q, -bound), bound);
        out[i] = q * d;
      }
      store8(y + base0 + (size_t)r * D_DIM, out);
    }
    if (v1) {
      float out[8];
#pragma unroll
      for (int i = 0; i < 8; ++i) {
        const bool mm = (m1 >> i) & 1u;
        const float d = mm ? os1 : sv1;
        const float bound = mm ? 127.0f : 7.0f;
        float q = rintf(cur1[i] / d);
        q = fminf(fmaxf(q, -bound), bound);
        out[i] = q * d;
      }
      store8(y + base1 + (size_t)r * D_DIM, out);
    }

#pragma unroll
    for (int i = 0; i < 8; ++i) { cur0[i] = nxt0[i]; cur1[i] = nxt1[i]; }
  }
}

// ---------------- fallback: exact sequential, runs only if speculation failed ----------------
__device__ __forceinline__ void grid_barrier(uint* cnt, uint* gen) {
  __syncthreads();
  if (threadIdx.x == 0) {
    const uint my = __hip_atomic_load(gen, __ATOMIC_ACQUIRE, __HIP_MEMORY_SCOPE_AGENT);
    const uint old = __hip_atomic_fetch_add(cnt, 1u, __ATOMIC_ACQ_REL, __HIP_MEMORY_SCOPE_AGENT);
    if (old == FB_NBLK - 1) {
      __hip_atomic_store(cnt, 0u, __ATOMIC_RELAXED, __HIP_MEMORY_SCOPE_AGENT);
      __hip_atomic_store(gen, my + 1u, __ATOMIC_RELEASE, __HIP_MEMORY_SCOPE_AGENT);
    } else {
      while (__hip_atomic_load(gen, __ATOMIC_ACQUIRE, __HIP_MEMORY_SCOPE_AGENT) == my)
        __builtin_amdgcn_s_sleep(8);
    }
  }
  __syncthreads();
}

__global__ __launch_bounds__(256, 2) void qact_fallback(
    const float* __restrict__ x, const float* __restrict__ s, float* __restrict__ y,
    const uint* __restrict__ flagset, uint* __restrict__ flags2, uint* __restrict__ bar) {
  // If every speculative flag came out 1, speculation was exact (induction) -> done.
  bool ok = true;
#pragma unroll
  for (int r = 0; r < R_STEPS; ++r) ok &= (flagset[r * 32] != 0u);
  if (ok) return;

  __shared__ float redM[4];
  __shared__ double redS[4][2];
  __shared__ float redO[4];

  const int tid = threadIdx.x, lane = tid & 63, wid = tid >> 6;
  u64 mask = 0;  // 7 rows x 8 bits

  for (int r = 0; r < R_STEPS; ++r) {
    // ---- phase A: exact flag contributions with current masks ----
    for (int j = 0; j < 7; ++j) {
      const int row = blockIdx.x + FB_NBLK * j;
      if (row >= NROWS) break;  // block-uniform
      const int b = row / G_TOK, g = row % G_TOK;
      const int tok = g * R_STEPS + r;
      float A = 0.0f;
      if (tok < L_TOK) {
        const size_t off = ((size_t)b * L_TOK + tok) * D_DIM + (size_t)tid * 8;
        float v[8];
        load8(v, x + off);
        const uint mj = (uint)(mask >> (j * 8)) & 0xffu;
#pragma unroll
        for (int i = 0; i < 8; ++i)
          if (!((mj >> i) & 1u)) A = fmaxf(A, fabsf(v[i]));
      }
#pragma unroll
      for (int o = 32; o > 0; o >>= 1) A = fmaxf(A, __shfl_down(A, o, 64));
      if (lane == 0) redM[wid] = A;
      __syncthreads();
      A = fmaxf(fmaxf(redM[0], redM[1]), fmaxf(redM[2], redM[3]));
      const float sv = (tok < L_TOK) ? s[tok] : 1.0f;
      if (tid == 0 && A / 7.0f > sv) atomicOr(&flags2[r * 32], 1u);
      __syncthreads();
    }

    grid_barrier(&bar[0], &bar[1]);

    const uint f = __hip_atomic_load(&flags2[r * 32], __ATOMIC_ACQUIRE, __HIP_MEMORY_SCOPE_AGENT);

    // ---- phase B: mask update (if f), quantize, store ----
    for (int j = 0; j < 7; ++j) {
      const int row = blockIdx.x + FB_NBLK * j;
      if (row >= NROWS) break;
      const int b = row / G_TOK, g = row % G_TOK;
      const int tok = g * R_STEPS + r;
      const bool valid = tok < L_TOK;
      const size_t off = ((size_t)b * L_TOK + (valid ? tok : 0)) * D_DIM + (size_t)tid * 8;
      float v[8];
      if (valid) load8(v, x + off);
      else zero8(v);
      uint mj = (uint)(mask >> (j * 8)) & 0xffu;
      float a[8];
#pragma unroll
      for (int i = 0; i < 8; ++i) a[i] = ((mj >> i) & 1u) ? 0.0f : fabsf(v[i]);
      if (f) {  // grid-uniform
        double S1 = 0.0, S2 = 0.0;
#pragma unroll
        for (int i = 0; i < 8; ++i) {
          S1 += (double)a[i];
          S2 += (double)a[i] * (double)a[i];
        }
#pragma unroll
        for (int o = 32; o > 0; o >>= 1) {
          S1 += __shfl_down(S1, o, 64);
          S2 += __shfl_down(S2, o, 64);
        }
        if (lane == 0) { redS[wid][0] = S1; redS[wid][1] = S2; }
        __syncthreads();
        S1 = redS[0][0] + redS[1][0] + redS[2][0] + redS[3][0];
        S2 = redS[0][1] + redS[1][1] + redS[2][1] + redS[3][1];
        const double n = (double)D_DIM;
        const double mean = S1 / n;
        double var = (S2 - n * mean * mean) / (n - 1.0);
        var = var > 0.0 ? var : 0.0;
        const double thr = mean + 3.0 * sqrt(var);
#pragma unroll
        for (int i = 0; i < 8; ++i)
          if ((double)a[i] > thr) mj |= (1u << i);
        mask = (mask & ~((u64)0xffu << (j * 8))) | ((u64)mj << (j * 8));
        __syncthreads();
      }
      if (valid) {
        float O = 0.0f;
#pragma unroll
        for (int i = 0; i < 8; ++i)
          if ((mj >> i) & 1u) O = fmaxf(O, fabsf(v[i]));
#pragma unroll
        for (int o = 32; o > 0; o >>= 1) O = fmaxf(O, __shfl_down(O, o, 64));
        if (lane == 0) redO[wid] = O;
        __syncthreads();
        O = fmaxf(fmaxf(redO[0], redO[1]), fmaxf(redO[2], redO[3]));
        const float os = fmaxf(O, 1e-8f) / 127.0f;
        const float sv = s[tok];
        float out[8];
#pragma unroll
        for (int i = 0; i < 8; ++i) {
          const bool mm = (mj >> i) & 1u;
          const float inl = mm ? 0.0f : v[i];
          const float orr = mm ? v[i] : 0.0f;
          const float qi = fminf(fmaxf(rintf(inl / sv), -7.0f), 7.0f);
          const float qo = fminf(fmaxf(rintf(orr / os), -127.0f), 127.0f);
          out[i] = qi * sv + qo * os;
        }
        store8(y + off, out);
        __syncthreads();
      }
    }
  }
}

extern "C" void kernel_launch(void* const* d_in, const int* in_sizes, int n_in,
                              void* d_out, int out_size, void* d_ws, size_t ws_size,
                              hipStream_t stream) {
  const float* x = (const float*)d_in[0];
  const float* s = (const float*)d_in[1];
  float* y = (float*)d_out;
  uint* flagset = (uint*)d_ws;
  uint* flags2 = (uint*)((char*)d_ws + 2048);
  uint* bar = (uint*)((char*)d_ws + 3968);

  (void)hipMemsetAsync(d_ws, 0, 4096, stream);
  qact_spec<<<NBLK, 256, 0, stream>>>(x, s, y, flagset);
  qact_fallback<<<FB_NBLK, 256, 0, stream>>>(x, s, y, flagset, flags2, bar);
}